// Round 11
// baseline (241.296 us; speedup 1.0000x reference)
//
#include <hip/hip_runtime.h>
#include <cstdint>
#include <cstddef>

typedef short bf16x8 __attribute__((ext_vector_type(8)));
typedef float f32x4 __attribute__((ext_vector_type(4)));

#define EPS 1e-3f
#define AT_OFF 13312   // shorts: at_lds = 32 rows x 104 shorts at smem[13312..16640)

__device__ __forceinline__ short f32_to_bf16s(float f) {
    union { float f; uint32_t u; } v; v.f = f;
    return (short)((v.u + 0x7FFFu + ((v.u >> 16) & 1u)) >> 16);
}

// K0: wt[kp][ci] = bf16(W[ci][kp]) (192x64); at[w][k] = bf16(A[p][v][w]) (32x96, k=p*25+v,
// zero-padded). Also seeds the work-queue counter to 1024 (blocks 0..1023 take their
// static id as first octet; queue serves octets 1024..1215).
__global__ __launch_bounds__(256) void prep_kernel(const float* __restrict__ A,
                                                   const float* __restrict__ W,
                                                   unsigned short* __restrict__ wt,
                                                   unsigned short* __restrict__ at,
                                                   unsigned int* __restrict__ ctr) {
    int idx = blockIdx.x * 256 + threadIdx.x;
    if (idx == 0) *ctr = 1024u;
    if (idx < 12288) {
        int kp = idx >> 6, ci = idx & 63;
        wt[idx] = (unsigned short)f32_to_bf16s(W[ci * 192 + kp]);
    } else {
        int j = idx - 12288;
        if (j < 3072) {
            int w = j / 96, k = j - w * 96;
            float val = 0.f;
            if (w < 25 && k < 75) {
                int p = k / 25, v = k - p * 25;
                val = A[(p * 25 + v) * 25 + w];
            }
            at[j] = (unsigned short)f32_to_bf16s(val);
        }
    }
}

__device__ __forceinline__ void load_a1(int g, const unsigned short* __restrict__ wt,
                                        int lcol, int q, bf16x8 (&a1)[3][2]) {
    #pragma unroll
    for (int mt = 0; mt < 3; ++mt)
        #pragma unroll
        for (int s = 0; s < 2; ++s)
            a1[mt][s] = *(const bf16x8*)(wt + (size_t)(g * 48 + mt * 16 + lcol) * 64 + 32 * s + 8 * q);
}

// One c-group: GEMM1 with pre-loaded a1, residual, stage->Ys, prefetch next a1,
// b2 from LDS (at_lds), GEMM2, BN+res epilogue. All statically indexed. (v9 verbatim)
__device__ __forceinline__ void do_group(int g, bool loadNext, int gnext,
    const unsigned short* __restrict__ wt, short* smem,
    const bf16x8 (&a1)[3][2], bf16x8 (&a1n)[3][2], const bf16x8 (&b1)[2][2],
    const float* __restrict__ x, float* __restrict__ out,
    const float* scs, const float* shs,
    size_t outrow, int lg, int wv, int q, int lcol)
{
    // GEMM1: M=48 (kp of group g), N=32 (own l, v+pad), K=64
    f32x4 acc[3][2];
    #pragma unroll
    for (int mt = 0; mt < 3; ++mt)
        #pragma unroll
        for (int nt = 0; nt < 2; ++nt) acc[mt][nt] = (f32x4){0.f, 0.f, 0.f, 0.f};
    #pragma unroll
    for (int s = 0; s < 2; ++s)
        #pragma unroll
        for (int mt = 0; mt < 3; ++mt) {
            bf16x8 av = a1[mt][s];
            #pragma unroll
            for (int nt = 0; nt < 2; ++nt)
                acc[mt][nt] = __builtin_amdgcn_mfma_f32_16x16x32_bf16(av, b1[nt][s], acc[mt][nt], 0, 0, 0);
        }

    // Residual prefetch (L2-hot: same rows fetched by phase 1 of this octet)
    float res[2][4];
    #pragma unroll
    for (int nt = 0; nt < 2; ++nt) {
        int w = nt * 16 + lcol;
        bool val = (w < 25) && (lg < 300);
        #pragma unroll
        for (int r = 0; r < 4; ++r) {
            int c = g * 16 + 4 * q + r;
            res[nt][r] = val ? x[outrow + (size_t)c * 7500 + w] : 0.f;
        }
    }

    // Stage D -> own Ys slab rows (wv*16+cl), col 25p+v  (wave-private, no barrier)
    #pragma unroll
    for (int mt = 0; mt < 3; ++mt)
        #pragma unroll
        for (int nt = 0; nt < 2; ++nt) {
            int v = nt * 16 + lcol;
            if (v < 25) {
                #pragma unroll
                for (int r = 0; r < 4; ++r) {
                    int kpl = mt * 16 + 4 * q + r;
                    int cl = kpl / 3, p = kpl - 3 * cl;
                    smem[(wv * 16 + cl) * 104 + 25 * p + v] = f32_to_bf16s(acc[mt][nt][r]);
                }
            }
        }

    // Prefetch next group's a1 now that acc is dead: lands under GEMM2 + epilogue.
    if (loadNext) load_a1(gnext, wt, lcol, q, a1n);

    // b2 fragments from at_lds (no persistent VGPR cost; ~120cy LDS, hideable)
    bf16x8 b2l[2][3];
    #pragma unroll
    for (int nt = 0; nt < 2; ++nt)
        #pragma unroll
        for (int s = 0; s < 3; ++s)
            b2l[nt][s] = *(const bf16x8*)&smem[AT_OFF + (nt * 16 + lcol) * 104 + 32 * s + 8 * q];

    // GEMM2: M=16 (cl), N=32 (w), K=96 — reads own slab (compiler orders via lgkmcnt)
    f32x4 c0 = {0.f, 0.f, 0.f, 0.f}, c1 = {0.f, 0.f, 0.f, 0.f};
    #pragma unroll
    for (int s = 0; s < 3; ++s) {
        bf16x8 a2 = *(const bf16x8*)&smem[(wv * 16 + lcol) * 104 + 32 * s + 8 * q];
        c0 = __builtin_amdgcn_mfma_f32_16x16x32_bf16(a2, b2l[0][s], c0, 0, 0, 0);
        c1 = __builtin_amdgcn_mfma_f32_16x16x32_bf16(a2, b2l[1][s], c1, 0, 0, 0);
    }

    // Epilogue: BN + ReLU + residual + ReLU
    if (lg < 300) {
        #pragma unroll
        for (int nt = 0; nt < 2; ++nt) {
            int w = nt * 16 + lcol;
            if (w < 25) {
                f32x4 cc = nt ? c1 : c0;
                #pragma unroll
                for (int r = 0; r < 4; ++r) {
                    int c = g * 16 + 4 * q + r;
                    float o = fmaxf(cc[r] * scs[c] + shs[c], 0.f);
                    out[outrow + (size_t)c * 7500 + w] = fmaxf(o + res[nt][r], 0.f);
                }
            }
        }
    }
}

// Mega v12 = v9's block (512 thr, 33.8KB LDS, 4 blocks/CU = 32 waves/CU, b2-in-LDS,
// a1 dbuf, XCD swizzle) made PERSISTENT: exactly 1024 blocks (all resident at t=0),
// pulling the 1216 (ch,n) octets from a global atomic queue. Removes the v9
// straggler round (192 CUs ran a 5th block nearly alone) at CONSTANT occupancy and
// VGPR — the un-confounded test v11 failed to run (its octet loop spilled: at-staging
// regs crossed the loop; here at is staged into the read-only LDS region pre-loop,
// and NO register state crosses an octet). Next-octet grab by lane 0 overlaps
// phase-1; published via the existing barrier. 3 barriers/octet (loop-top guard).
__global__ __launch_bounds__(512, 4) void mega_kernel(
    const float* __restrict__ x,
    const unsigned short* __restrict__ wt,
    const unsigned short* __restrict__ at,
    const float* __restrict__ gamma, const float* __restrict__ beta,
    const float* __restrict__ mean, const float* __restrict__ var,
    float* __restrict__ out,
    unsigned int* __restrict__ ctr) {
    const int tid = threadIdx.x;
    const int wv = tid >> 6, lane = tid & 63, q = lane >> 4, lcol = lane & 15;

    __shared__ __align__(16) short smem[16640];   // [0,13312) xwL<->Ys | [13312,16640) at_lds
    __shared__ float scs[64], shs[64];
    __shared__ int s_next;

    // at -> LDS once per block (read-only region; survives all octets). These regs
    // die before the octet loop — nothing crosses iterations (v11 spill lesson).
    {
        const int aw = tid >> 4, aj = (tid & 15) * 6;
        const uint32_t* asrc = (const uint32_t*)(at + aw * 96 + aj);
        uint32_t a0 = asrc[0], a1v = asrc[1], a2v = asrc[2];
        uint32_t* adst = (uint32_t*)&smem[AT_OFF + aw * 104 + aj];
        adst[0] = a0; adst[1] = a1v; adst[2] = a2v;
    }
    if (tid < 64) {
        float sc = gamma[tid] * rsqrtf(var[tid] + EPS);
        scs[tid] = sc;
        shs[tid] = beta[tid] - mean[tid] * sc;
    }
    // (no barrier needed here: at_lds/scs writes are visible after barrier 1 below,
    //  which precedes every read of them)

    int oct = blockIdx.x + 32 * blockIdx.y;   // first octet = static id (ctr starts at 1024)

    #pragma unroll 1
    while (oct < 1216) {
        // XCD-chunked swizzle (v7-verified): bijective over 0..1215 (1216 = 8*152).
        const int logical = (oct & 7) * 152 + (oct >> 3);
        const int ch = logical % 38;
        const int n  = logical / 38;
        const int l0 = ch * 8;

        // Phase 1: per-(ci,v) running 9-window over l = l0..l0+7 -> xwL (bf16)
        #pragma unroll 1
        for (int rep = 0; rep < 4; ++rep) {
            int cidx = tid + rep * 512;
            if (cidx < 1600) {
                int ci = cidx / 25, v = cidx - ci * 25;
                const float* xp = x + (size_t)(n * 64 + ci) * 7500 + v;
                float vals[16];
                #pragma unroll
                for (int i = 0; i < 16; ++i) {
                    int l = l0 - 8 + i;
                    vals[i] = (l >= 0 && l < 300) ? xp[l * 25] : 0.f;
                }
                float run = vals[0] + vals[1] + vals[2] + vals[3]
                          + vals[4] + vals[5] + vals[6] + vals[7];
                short* wb = &smem[(ci >> 3) * 1656 + (ci & 7)];
                #pragma unroll
                for (int j = 0; j < 8; ++j) {
                    run += vals[j + 8];
                    wb[(j * 25 + v) * 8] = f32_to_bf16s(run);
                    run -= vals[j];
                }
            }
        }

        // Grab next octet while phase-1 traffic drains; published by barrier 1.
        if (tid == 0) s_next = (int)atomicAdd(ctr, 1u);
        __syncthreads();   // barrier 1: xwL (+at_lds, scs on first octet) ready

        // b1 fragments: B[k=ci][col], cols wv*25 + nt*16 + lcol (<=206; cols>=200 are
        // stale-but-finite garbage whose D-columns map to w>=25 and are never stored)
        bf16x8 b1[2][2];
        #pragma unroll
        for (int nt = 0; nt < 2; ++nt) {
            int col = wv * 25 + nt * 16 + lcol;
            #pragma unroll
            for (int s = 0; s < 2; ++s)
                b1[nt][s] = *(const bf16x8*)&smem[(4 * s + q) * 1656 + col * 8];
        }
        const int next = s_next;   // read between barriers (next write is 2 barriers away)
        __syncthreads();   // barrier 2: all xwL reads done; smem[0,13312) becomes Ys

        // Zero own Ys slab pad cols [72,104) (re-zero: phase-1 clobbered the region)
        #pragma unroll
        for (int i = lane; i < 512; i += 64) {
            int r = i >> 5, cc = 72 + (i & 31);
            smem[(wv * 16 + r) * 104 + cc] = 0;
        }

        const int lg = l0 + wv;
        const size_t outrow = ((size_t)n * 64 * 300 + lg) * 25;   // + c*7500 + w

        // Manually unrolled 4-group pipeline with a1 double-buffer (static indexing)
        bf16x8 a1a[3][2], a1b[3][2];
        load_a1(0, wt, lcol, q, a1a);
        do_group(0, true,  1, wt, smem, a1a, a1b, b1, x, out, scs, shs, outrow, lg, wv, q, lcol);
        __builtin_amdgcn_sched_barrier(0);
        do_group(1, true,  2, wt, smem, a1b, a1a, b1, x, out, scs, shs, outrow, lg, wv, q, lcol);
        __builtin_amdgcn_sched_barrier(0);
        do_group(2, true,  3, wt, smem, a1a, a1b, b1, x, out, scs, shs, outrow, lg, wv, q, lcol);
        __builtin_amdgcn_sched_barrier(0);
        do_group(3, false, 3, wt, smem, a1b, a1a, b1, x, out, scs, shs, outrow, lg, wv, q, lcol);

        oct = next;
        __syncthreads();   // loop-top guard: all waves' Ys reads done before next
                           // octet's phase-1 overwrites the aliased region
    }
}

extern "C" void kernel_launch(void* const* d_in, const int* in_sizes, int n_in,
                              void* d_out, int out_size, void* d_ws, size_t ws_size,
                              hipStream_t stream) {
    const float* x     = (const float*)d_in[0];
    const float* A     = (const float*)d_in[1];
    const float* W     = (const float*)d_in[2];
    const float* gamma = (const float*)d_in[3];
    const float* beta  = (const float*)d_in[4];
    const float* mean  = (const float*)d_in[5];
    const float* var   = (const float*)d_in[6];
    float* out = (float*)d_out;

    char* ws = (char*)d_ws;
    unsigned short* wt = (unsigned short*)ws;               // 24,576 B
    unsigned short* at = (unsigned short*)(ws + 24576);     // 6,144 B
    unsigned int*  ctr = (unsigned int*)(ws + 30720);       // 4 B work-queue counter

    prep_kernel<<<60, 256, 0, stream>>>(A, W, wt, at, ctr);
    mega_kernel<<<dim3(32, 32), 512, 0, stream>>>(x, wt, at, gamma, beta, mean, var, out, ctr);
}

// Round 12
// 162.391 us; speedup vs baseline: 1.4859x; 1.4859x over previous
//
#include <hip/hip_runtime.h>
#include <cstdint>
#include <cstddef>

typedef short bf16x8 __attribute__((ext_vector_type(8)));
typedef float f32x4 __attribute__((ext_vector_type(4)));

#define EPS 1e-3f
#define AT_OFF 13312   // shorts: at_lds = 32 rows x 104 shorts at smem[13312..16640)

__device__ __forceinline__ short f32_to_bf16s(float f) {
    union { float f; uint32_t u; } v; v.f = f;
    return (short)((v.u + 0x7FFFu + ((v.u >> 16) & 1u)) >> 16);
}

// K0: wt[kp][ci] = bf16(W[ci][kp]) (192x64); at[w][k] = bf16(A[p][v][w]) (32x96, k=p*25+v, zero-padded)
__global__ __launch_bounds__(256) void prep_kernel(const float* __restrict__ A,
                                                   const float* __restrict__ W,
                                                   unsigned short* __restrict__ wt,
                                                   unsigned short* __restrict__ at) {
    int idx = blockIdx.x * 256 + threadIdx.x;
    if (idx < 12288) {
        int kp = idx >> 6, ci = idx & 63;
        wt[idx] = (unsigned short)f32_to_bf16s(W[ci * 192 + kp]);
    } else {
        int j = idx - 12288;
        if (j < 3072) {
            int w = j / 96, k = j - w * 96;
            float val = 0.f;
            if (w < 25 && k < 75) {
                int p = k / 25, v = k - p * 25;
                val = A[(p * 25 + v) * 25 + w];
            }
            at[j] = (unsigned short)f32_to_bf16s(val);
        }
    }
}

__device__ __forceinline__ void load_a1(int g, const unsigned short* __restrict__ wt,
                                        int lcol, int q, bf16x8 (&a1)[3][2]) {
    #pragma unroll
    for (int mt = 0; mt < 3; ++mt)
        #pragma unroll
        for (int s = 0; s < 2; ++s)
            a1[mt][s] = *(const bf16x8*)(wt + (size_t)(g * 48 + mt * 16 + lcol) * 64 + 32 * s + 8 * q);
}

// One c-group: GEMM1 with pre-loaded a1, residual, stage->Ys, prefetch next a1,
// b2 from LDS (at_lds), GEMM2, BN+res epilogue. All statically indexed.
__device__ __forceinline__ void do_group(int g, bool loadNext, int gnext,
    const unsigned short* __restrict__ wt, short* smem,
    const bf16x8 (&a1)[3][2], bf16x8 (&a1n)[3][2], const bf16x8 (&b1)[2][2],
    const float* __restrict__ x, float* __restrict__ out,
    const float* scs, const float* shs,
    size_t outrow, int lg, int wv, int q, int lcol)
{
    // GEMM1: M=48 (kp of group g), N=32 (own l, v+pad), K=64
    f32x4 acc[3][2];
    #pragma unroll
    for (int mt = 0; mt < 3; ++mt)
        #pragma unroll
        for (int nt = 0; nt < 2; ++nt) acc[mt][nt] = (f32x4){0.f, 0.f, 0.f, 0.f};
    #pragma unroll
    for (int s = 0; s < 2; ++s)
        #pragma unroll
        for (int mt = 0; mt < 3; ++mt) {
            bf16x8 av = a1[mt][s];
            #pragma unroll
            for (int nt = 0; nt < 2; ++nt)
                acc[mt][nt] = __builtin_amdgcn_mfma_f32_16x16x32_bf16(av, b1[nt][s], acc[mt][nt], 0, 0, 0);
        }

    // Residual prefetch (L2-hot: same rows fetched by phase 1 of this block)
    float res[2][4];
    #pragma unroll
    for (int nt = 0; nt < 2; ++nt) {
        int w = nt * 16 + lcol;
        bool val = (w < 25) && (lg < 300);
        #pragma unroll
        for (int r = 0; r < 4; ++r) {
            int c = g * 16 + 4 * q + r;
            res[nt][r] = val ? x[outrow + (size_t)c * 7500 + w] : 0.f;
        }
    }

    // Stage D -> own Ys slab rows (wv*16+cl), col 25p+v  (wave-private, no barrier)
    #pragma unroll
    for (int mt = 0; mt < 3; ++mt)
        #pragma unroll
        for (int nt = 0; nt < 2; ++nt) {
            int v = nt * 16 + lcol;
            if (v < 25) {
                #pragma unroll
                for (int r = 0; r < 4; ++r) {
                    int kpl = mt * 16 + 4 * q + r;
                    int cl = kpl / 3, p = kpl - 3 * cl;
                    smem[(wv * 16 + cl) * 104 + 25 * p + v] = f32_to_bf16s(acc[mt][nt][r]);
                }
            }
        }

    // Prefetch next group's a1 now that acc is dead: lands under GEMM2 + epilogue.
    if (loadNext) load_a1(gnext, wt, lcol, q, a1n);

    // b2 fragments from at_lds (no persistent VGPR cost; ~120cy LDS, hideable)
    bf16x8 b2l[2][3];
    #pragma unroll
    for (int nt = 0; nt < 2; ++nt)
        #pragma unroll
        for (int s = 0; s < 3; ++s)
            b2l[nt][s] = *(const bf16x8*)&smem[AT_OFF + (nt * 16 + lcol) * 104 + 32 * s + 8 * q];

    // GEMM2: M=16 (cl), N=32 (w), K=96 — reads own slab (compiler orders via lgkmcnt)
    f32x4 c0 = {0.f, 0.f, 0.f, 0.f}, c1 = {0.f, 0.f, 0.f, 0.f};
    #pragma unroll
    for (int s = 0; s < 3; ++s) {
        bf16x8 a2 = *(const bf16x8*)&smem[(wv * 16 + lcol) * 104 + 32 * s + 8 * q];
        c0 = __builtin_amdgcn_mfma_f32_16x16x32_bf16(a2, b2l[0][s], c0, 0, 0, 0);
        c1 = __builtin_amdgcn_mfma_f32_16x16x32_bf16(a2, b2l[1][s], c1, 0, 0, 0);
    }

    // Epilogue: BN + ReLU + residual + ReLU
    if (lg < 300) {
        #pragma unroll
        for (int nt = 0; nt < 2; ++nt) {
            int w = nt * 16 + lcol;
            if (w < 25) {
                f32x4 cc = nt ? c1 : c0;
                #pragma unroll
                for (int r = 0; r < 4; ++r) {
                    int c = g * 16 + 4 * q + r;
                    float o = fmaxf(cc[r] * scs[c] + shs[c], 0.f);
                    out[outrow + (size_t)c * 7500 + w] = fmaxf(o + res[nt][r], 0.f);
                }
            }
        }
    }
}

// Mega v13 = v9 restored verbatim (session best, 70.4us): 1 sample/block, 4 blocks/CU
// = 32 waves/CU, XCD swizzle, b2-in-LDS, a1 double-buffer, stride-104 Ys.
// Refuted this session: occupancy-trading restructures (v3/v6), register pipelining
// (v2/v4/v5/v8), entry stagger (v10), loop-wrapped multi-tile / persistent queue
// (v11/v12 — any loop around the body spills past the 64-VGPR cap).
__global__ __launch_bounds__(512, 4) void mega_kernel(
    const float* __restrict__ x,
    const unsigned short* __restrict__ wt,
    const unsigned short* __restrict__ at,
    const float* __restrict__ gamma, const float* __restrict__ beta,
    const float* __restrict__ mean, const float* __restrict__ var,
    float* __restrict__ out) {
    // XCD-chunked swizzle (v7-verified: FETCH 92->44 MB): bijective, 1216 = 8*152.
    const int lin = blockIdx.x + 38 * blockIdx.y;        // 0..1215
    const int logical = (lin & 7) * 152 + (lin >> 3);
    const int ch = logical % 38;
    const int n  = logical / 38;

    const int l0 = ch * 8;
    const int tid = threadIdx.x;
    const int wv = tid >> 6, lane = tid & 63, q = lane >> 4, lcol = lane & 15;

    __shared__ __align__(16) short smem[16640];   // [0,13312) xwL->Ys | [13312,16640) at_lds
    __shared__ float scs[64], shs[64];

    // at staging: issue 3 dwords/thread early (512 threads x 12B = 6144B = all of at);
    // written to LDS (stride-104 pad rows) after phase-1, before barrier 1.
    const int aw = tid >> 4, aj = (tid & 15) * 6;
    const uint32_t* asrc = (const uint32_t*)(at + aw * 96 + aj);
    uint32_t av0 = asrc[0], av1 = asrc[1], av2 = asrc[2];
    __builtin_amdgcn_sched_barrier(0);   // pin: at-loads stay above phase-1 (anti-sink)

    if (tid < 64) {
        float sc = gamma[tid] * rsqrtf(var[tid] + EPS);
        scs[tid] = sc;
        shs[tid] = beta[tid] - mean[tid] * sc;
    }

    // Phase 1: per-(ci,v) running 9-window over l = l0..l0+7 -> xwL (bf16)
    #pragma unroll 1
    for (int rep = 0; rep < 4; ++rep) {
        int cidx = tid + rep * 512;
        if (cidx < 1600) {
            int ci = cidx / 25, v = cidx - ci * 25;
            const float* xp = x + (size_t)(n * 64 + ci) * 7500 + v;
            float vals[16];
            #pragma unroll
            for (int i = 0; i < 16; ++i) {
                int l = l0 - 8 + i;
                vals[i] = (l >= 0 && l < 300) ? xp[l * 25] : 0.f;
            }
            float run = vals[0] + vals[1] + vals[2] + vals[3]
                      + vals[4] + vals[5] + vals[6] + vals[7];
            short* wb = &smem[(ci >> 3) * 1656 + (ci & 7)];
            #pragma unroll
            for (int j = 0; j < 8; ++j) {
                run += vals[j + 8];
                wb[(j * 25 + v) * 8] = f32_to_bf16s(run);
                run -= vals[j];
            }
        }
    }

    // at -> LDS (the 3 dwords have long since landed)
    {
        uint32_t* adst = (uint32_t*)&smem[AT_OFF + aw * 104 + aj];
        adst[0] = av0; adst[1] = av1; adst[2] = av2;
    }
    __syncthreads();   // barrier 1: xwL + at_lds ready

    // b1 fragments: B[k=ci][col], cols wv*25 + nt*16 + lcol (<=206; cols>=200 are
    // stale-but-finite garbage whose D-columns map to w>=25 and are never stored)
    bf16x8 b1[2][2];
    #pragma unroll
    for (int nt = 0; nt < 2; ++nt) {
        int col = wv * 25 + nt * 16 + lcol;
        #pragma unroll
        for (int s = 0; s < 2; ++s)
            b1[nt][s] = *(const bf16x8*)&smem[(4 * s + q) * 1656 + col * 8];
    }
    __syncthreads();   // barrier 2: all xwL reads done; smem[0,13312) becomes Ys

    // Zero own Ys slab pad cols [72,104): wave-private from here on.
    #pragma unroll
    for (int i = lane; i < 512; i += 64) {
        int r = i >> 5, cc = 72 + (i & 31);
        smem[(wv * 16 + r) * 104 + cc] = 0;
    }

    const int lg = l0 + wv;
    const size_t outrow = ((size_t)n * 64 * 300 + lg) * 25;   // + c*7500 + w

    // Manually unrolled 4-group pipeline with a1 double-buffer (static indexing only)
    bf16x8 a1a[3][2], a1b[3][2];
    load_a1(0, wt, lcol, q, a1a);
    do_group(0, true,  1, wt, smem, a1a, a1b, b1, x, out, scs, shs, outrow, lg, wv, q, lcol);
    __builtin_amdgcn_sched_barrier(0);
    do_group(1, true,  2, wt, smem, a1b, a1a, b1, x, out, scs, shs, outrow, lg, wv, q, lcol);
    __builtin_amdgcn_sched_barrier(0);
    do_group(2, true,  3, wt, smem, a1a, a1b, b1, x, out, scs, shs, outrow, lg, wv, q, lcol);
    __builtin_amdgcn_sched_barrier(0);
    do_group(3, false, 3, wt, smem, a1b, a1a, b1, x, out, scs, shs, outrow, lg, wv, q, lcol);
}

extern "C" void kernel_launch(void* const* d_in, const int* in_sizes, int n_in,
                              void* d_out, int out_size, void* d_ws, size_t ws_size,
                              hipStream_t stream) {
    const float* x     = (const float*)d_in[0];
    const float* A     = (const float*)d_in[1];
    const float* W     = (const float*)d_in[2];
    const float* gamma = (const float*)d_in[3];
    const float* beta  = (const float*)d_in[4];
    const float* mean  = (const float*)d_in[5];
    const float* var   = (const float*)d_in[6];
    float* out = (float*)d_out;

    char* ws = (char*)d_ws;
    unsigned short* wt = (unsigned short*)ws;               // 24,576 B
    unsigned short* at = (unsigned short*)(ws + 24576);     // 6,144 B

    prep_kernel<<<60, 256, 0, stream>>>(A, W, wt, at);
    mega_kernel<<<dim3(38, 32), 512, 0, stream>>>(x, wt, at, gamma, beta, mean, var, out);
}